// Round 15
// baseline (32.772 us; speedup 1.0000x reference)
//
#include <hip/hip_runtime.h>

// B=1048576, N=5, H=2, CLS=24, OUT=5.  h0=c0=0 -> w_hh dead, f-gate dead.
// Round-15: v11 base (zero-LDS FC via permlane32_swap + 32x32x16 MFMA) with
// ONE change: wave-cooperative `others` load. Six designs all plateau at
// 29-33us; the only never-varied component is others' access pattern
// (7 float2 loads @56B stride = ~28 L1/TA line-segments per instruction,
// ~196/wave-group, TA is per-CU shared -> hidden serial floor). Now: the
// wave's contiguous 3584B slab is fetched with 4 coalesced dwordx4 into a
// wave-private LDS slab, then each lane ds_reads its own 14 floats (7x b64).
// TA line-work per wave-group: ~216 -> ~52.

constexpr int Bc = 1048576;
constexpr int Nc = 5;

typedef __attribute__((ext_vector_type(8))) short bf16x8;
typedef __attribute__((ext_vector_type(16))) float f32x16;

__device__ __forceinline__ unsigned cvtpk(float lo, float hi) {
    unsigned r;
    asm("v_cvt_pk_bf16_f32 %0, %1, %2" : "=v"(r) : "v"(lo), "v"(hi));
    return r;
}
// v_permlane32_swap_b32 x, y:  x.lanes[32:63] <-> y.lanes[0:31]
__device__ __forceinline__ void swap32(unsigned &x, unsigned &y) {
    asm("v_permlane32_swap_b32 %0, %1" : "+v"(x), "+v"(y));
}
__device__ __forceinline__ float fast_sigmoid(float x) {
    return __builtin_amdgcn_rcpf(1.0f + __expf(-x));
}
// sigmoid(a)*tanh(b) with a single rcp
__device__ __forceinline__ float sigtanh(float a, float b) {
    float ea = __expf(-a);
    float eb = __expf(2.0f * b);
    return (eb - 1.0f) * __builtin_amdgcn_rcpf((eb + 1.0f) * (1.0f + ea));
}
__device__ __forceinline__ bf16x8 mk_frag(unsigned a, unsigned b,
                                          unsigned c, unsigned d) {
    union { uint4 u; bf16x8 v; } x;
    x.u = make_uint4(a, b, c, d);
    return x.v;
}
__device__ __forceinline__ bf16x8 pack_row8(const float* row, bool valid) {
    unsigned h0 = 0, h1 = 0, h2 = 0, h3 = 0;
    if (valid) {
        float4 a = *reinterpret_cast<const float4*>(row);
        float4 b = *reinterpret_cast<const float4*>(row + 4);
        h0 = cvtpk(a.x, a.y); h1 = cvtpk(a.z, a.w);
        h2 = cvtpk(b.x, b.y); h3 = cvtpk(b.z, b.w);
    }
    return mk_frag(h0, h1, h2, h3);
}

__global__ __launch_bounds__(256) void fused_rnn_mlp_v15(
    const float* __restrict__ seqs,    // [N,1,B,2]
    const float* __restrict__ others,  // [1,B,14]
    const float* __restrict__ w_ih,    // [N,8,2]
    const float* __restrict__ b_ih,    // [N,8]
    const float* __restrict__ b_hh,    // [N,8]
    const float* __restrict__ w1,      // [24,24]
    const float* __restrict__ b1,      // [24]
    const float* __restrict__ w2,      // [5,24]
    const float* __restrict__ b2,      // [5]
    float* __restrict__ out)           // [B,5]
{
    // wave-private slabs: 64 elems x 14 f32 = 3584 B each
    __shared__ float lds_oth[4][896];

    const int tid  = threadIdx.x;
    const int lane = tid & 63;
    const int wid  = tid >> 6;
    const int lo31 = lane & 31;        // elem-in-tile / weight row
    const int kh   = lane >> 5;        // 0: lanes 0-31, 1: lanes 32-63
    const int base = blockIdx.x * 512; // 2 groups x 256 elems

    // ---------- group-invariant: A-fragments + C1 bias init ----------
    const bf16x8 A1a = pack_row8(w1 + lo31 * 24 + 8 * kh, lo31 < 24);
    const bf16x8 A1b = pack_row8(w1 + lo31 * 24 + 16, (lo31 < 24) && (kh == 0));
    const bf16x8 A2a = pack_row8(w2 + lo31 * 24 + 8 * kh, lo31 < 5);
    const bf16x8 A2b = pack_row8(w2 + lo31 * 24 + 16, (lo31 < 5) && (kh == 0));

    f32x16 c1z;
#pragma unroll
    for (int r = 0; r < 16; r++) {
        const int jb = (r & 3) + 8 * (r >> 2);        // row for kh=0
        float v = 0.0f;
        if (jb < 24) v = kh ? b1[jb + 4] : b1[jb];
        c1z[r] = v;
    }

#pragma unroll
    for (int g = 0; g < 2; g++) {
        const int elem  = base + g * 256 + tid;
        const int wele  = base + g * 256 + wid * 64;   // wave's first elem
        const int wbase = wele;

        // ---------- seqs: per-lane coalesced float2 (4 lines/instr, ideal) ----------
        float2 x[Nc];
#pragma unroll
        for (int n = 0; n < Nc; n++)
            x[n] = *reinterpret_cast<const float2*>(
                seqs + ((size_t)n * Bc + elem) * 2);

        // ---------- others: wave-cooperative coalesced load via LDS slab ----------
        float2 oth[7];
        {
            const float4* src =
                reinterpret_cast<const float4*>(others + (size_t)wele * 14);
            float4* dst = reinterpret_cast<float4*>(lds_oth[wid]);
            // 896 floats = 224 float4; 64 lanes x 4 rounds (last half-masked)
#pragma unroll
            for (int j = 0; j < 3; j++) dst[lane + 64 * j] = src[lane + 64 * j];
            if (lane < 32) dst[lane + 192] = src[lane + 192];
            // DS pipe is in-order per wave; fence cheap insurance vs reordering
            asm volatile("s_waitcnt lgkmcnt(0)" ::: "memory");
            const float2* me =
                reinterpret_cast<const float2*>(lds_oth[wid] + lane * 14);
#pragma unroll
            for (int r = 0; r < 7; r++) oth[r] = me[r];
        }

        // ---------- LSTM (one step, h0=c0=0); pack feats into d[12] ----------
        unsigned d[12];
#pragma unroll
        for (int n = 0; n < Nc; n++) {
            const float* w = w_ih + n * 16;   // gate rows i(0,1) f(2,3) g(4,5) o(6,7)
            const float bi0 = b_ih[n*8+0] + b_hh[n*8+0];
            const float bi1 = b_ih[n*8+1] + b_hh[n*8+1];
            const float bg0 = b_ih[n*8+4] + b_hh[n*8+4];
            const float bg1 = b_ih[n*8+5] + b_hh[n*8+5];
            const float bo0 = b_ih[n*8+6] + b_hh[n*8+6];
            const float bo1 = b_ih[n*8+7] + b_hh[n*8+7];
            float gi0 = fmaf(x[n].x, w[0],  fmaf(x[n].y, w[1],  bi0));
            float gi1 = fmaf(x[n].x, w[2],  fmaf(x[n].y, w[3],  bi1));
            float gg0 = fmaf(x[n].x, w[8],  fmaf(x[n].y, w[9],  bg0));
            float gg1 = fmaf(x[n].x, w[10], fmaf(x[n].y, w[11], bg1));
            float go0 = fmaf(x[n].x, w[12], fmaf(x[n].y, w[13], bo0));
            float go1 = fmaf(x[n].x, w[14], fmaf(x[n].y, w[15], bo1));
            float c0 = sigtanh(gi0, gg0);
            float c1 = sigtanh(gi1, gg1);
            d[n] = cvtpk(sigtanh(go0, c0), sigtanh(go1, c1));
        }
#pragma unroll
        for (int j = 0; j < 7; j++)
            d[5 + j] = cvtpk(oth[j].x, oth[j].y);

        // ---------- FC1 B-fragments via permlane32_swap (dual-output) ----------
        unsigned b0a[4], b1a[4], b0b[4], b1b[4];
#pragma unroll
        for (int i = 0; i < 4; i++) {
            b0a[i] = d[i];     b1a[i] = d[4 + i];  swap32(b0a[i], b1a[i]);
            b0b[i] = d[8 + i]; b1b[i] = 0u;        swap32(b0b[i], b1b[i]);
        }

        // ---------- FC1: 4 MFMAs (2 K-chunks x 2 tiles) ----------
        f32x16 accA = c1z, accB = c1z;
        accA = __builtin_amdgcn_mfma_f32_32x32x16_bf16(
            A1a, mk_frag(b0a[0], b0a[1], b0a[2], b0a[3]), accA, 0, 0, 0);
        accA = __builtin_amdgcn_mfma_f32_32x32x16_bf16(
            A1b, mk_frag(b0b[0], b0b[1], b0b[2], b0b[3]), accA, 0, 0, 0);
        accB = __builtin_amdgcn_mfma_f32_32x32x16_bf16(
            A1a, mk_frag(b1a[0], b1a[1], b1a[2], b1a[3]), accB, 0, 0, 0);
        accB = __builtin_amdgcn_mfma_f32_32x32x16_bf16(
            A1b, mk_frag(b1b[0], b1b[1], b1b[2], b1b[3]), accB, 0, 0, 0);

        // ---------- FC2 + sigmoid + store, per tile ----------
#pragma unroll
        for (int t = 0; t < 2; t++) {
            const f32x16 acc = t ? accB : accA;
            unsigned p0 = cvtpk(fmaxf(acc[0],  0.f), fmaxf(acc[1],  0.f));
            unsigned p1 = cvtpk(fmaxf(acc[2],  0.f), fmaxf(acc[3],  0.f));
            unsigned p2 = cvtpk(fmaxf(acc[4],  0.f), fmaxf(acc[5],  0.f));
            unsigned p3 = cvtpk(fmaxf(acc[6],  0.f), fmaxf(acc[7],  0.f));
            unsigned p4 = cvtpk(fmaxf(acc[8],  0.f), fmaxf(acc[9],  0.f));
            unsigned p5 = cvtpk(fmaxf(acc[10], 0.f), fmaxf(acc[11], 0.f));
            // B2a words: {p0|q2, p1|q3, q0|p2, q1|p3} via 2 swaps
            unsigned w0 = p0, w2 = p2;  swap32(w0, w2);
            unsigned w1v = p1, w3 = p3; swap32(w1v, w3);
            // B2b words: {p4|0, p5|0, q4|0, q5|0} via 2 swaps with zero
            unsigned u0 = p4, u2 = 0u;  swap32(u0, u2);
            unsigned u1 = p5, u3 = 0u;  swap32(u1, u3);
            const bf16x8 B2a = mk_frag(w0, w1v, w2, w3);
            const bf16x8 B2b = mk_frag(u0, u1, u2, u3);

            f32x16 c2;
#pragma unroll
            for (int r = 0; r < 16; r++) c2[r] = 0.0f;
            c2[0] = kh ? b2[4] : b2[0];
            if (!kh) { c2[1] = b2[1]; c2[2] = b2[2]; c2[3] = b2[3]; }
            c2 = __builtin_amdgcn_mfma_f32_32x32x16_bf16(A2a, B2a, c2, 0, 0, 0);
            c2 = __builtin_amdgcn_mfma_f32_32x32x16_bf16(A2b, B2b, c2, 0, 0, 0);

            const float s0 = fast_sigmoid(c2[0]);
            const float s1 = fast_sigmoid(c2[1]);
            const float s2 = fast_sigmoid(c2[2]);
            const float s3 = fast_sigmoid(c2[3]);
            const int et = wbase + t * 32 + lo31;
            float* o = out + (size_t)et * 5;
            if (kh == 0) {          // rows q=0..3
                o[0] = s0; o[1] = s1; o[2] = s2; o[3] = s3;
            } else {                // row q=4 (reg 0)
                o[4] = s0;
            }
        }
    }
}

extern "C" void kernel_launch(void* const* d_in, const int* in_sizes, int n_in,
                              void* d_out, int out_size, void* d_ws, size_t ws_size,
                              hipStream_t stream) {
    const float* seqs   = (const float*)d_in[0];
    const float* others = (const float*)d_in[1];
    const float* w_ih   = (const float*)d_in[2];
    // d_in[3] = w_hh : dead (h0 = 0)
    const float* b_ih   = (const float*)d_in[4];
    const float* b_hh   = (const float*)d_in[5];
    const float* w1     = (const float*)d_in[6];
    const float* b1     = (const float*)d_in[7];
    const float* w2     = (const float*)d_in[8];
    const float* b2     = (const float*)d_in[9];
    float* out = (float*)d_out;

    dim3 grid(Bc / 512), block(256);
    fused_rnn_mlp_v15<<<grid, block, 0, stream>>>(
        seqs, others, w_ih, b_ih, b_hh, w1, b1, w2, b2, out);
}

// Round 17
// 32.401 us; speedup vs baseline: 1.0114x; 1.0114x over previous
//
#include <hip/hip_runtime.h>

// B=1048576, N=5, H=2, CLS=24, OUT=5.  h0=c0=0 -> w_hh dead, f-gate dead.
// Round-16 resubmit (infra failure; kernel never ran). TWO consecutive
// elements per lane: every input load becomes a 16B dwordx4 (12 loads per
// 2 elems vs 24 float2) and per-wave in-flight bytes double -> attacks the
// weak-MLP latency-bound profile (7 designs flat at ~30us, all pipes <45%).
// The wave's 128 elems form 4 MFMA tiles (h=lane-half, p=parity): tile(h,p)
// col c = element wbase+64h+2c+p. v11's HW-validated swap32 fragment algebra
// applies verbatim per parity; parities sequential to cap live accumulators.

constexpr int Bc = 1048576;
constexpr int Nc = 5;

typedef __attribute__((ext_vector_type(8))) short bf16x8;
typedef __attribute__((ext_vector_type(16))) float f32x16;

__device__ __forceinline__ unsigned cvtpk(float lo, float hi) {
    unsigned r;
    asm("v_cvt_pk_bf16_f32 %0, %1, %2" : "=v"(r) : "v"(lo), "v"(hi));
    return r;
}
// v_permlane32_swap_b32 x, y:  x.lanes[32:63] <-> y.lanes[0:31]
__device__ __forceinline__ void swap32(unsigned &x, unsigned &y) {
    asm("v_permlane32_swap_b32 %0, %1" : "+v"(x), "+v"(y));
}
__device__ __forceinline__ float fast_sigmoid(float x) {
    return __builtin_amdgcn_rcpf(1.0f + __expf(-x));
}
// sigmoid(a)*tanh(b) with a single rcp
__device__ __forceinline__ float sigtanh(float a, float b) {
    float ea = __expf(-a);
    float eb = __expf(2.0f * b);
    return (eb - 1.0f) * __builtin_amdgcn_rcpf((eb + 1.0f) * (1.0f + ea));
}
__device__ __forceinline__ bf16x8 mk_frag(unsigned a, unsigned b,
                                          unsigned c, unsigned d) {
    union { uint4 u; bf16x8 v; } x;
    x.u = make_uint4(a, b, c, d);
    return x.v;
}
__device__ __forceinline__ bf16x8 pack_row8(const float* row, bool valid) {
    unsigned h0 = 0, h1 = 0, h2 = 0, h3 = 0;
    if (valid) {
        float4 a = *reinterpret_cast<const float4*>(row);
        float4 b = *reinterpret_cast<const float4*>(row + 4);
        h0 = cvtpk(a.x, a.y); h1 = cvtpk(a.z, a.w);
        h2 = cvtpk(b.x, b.y); h3 = cvtpk(b.z, b.w);
    }
    return mk_frag(h0, h1, h2, h3);
}

__global__ __launch_bounds__(256) void fused_rnn_mlp_v16(
    const float* __restrict__ seqs,    // [N,1,B,2]
    const float* __restrict__ others,  // [1,B,14]
    const float* __restrict__ w_ih,    // [N,8,2]
    const float* __restrict__ b_ih,    // [N,8]
    const float* __restrict__ b_hh,    // [N,8]
    const float* __restrict__ w1,      // [24,24]
    const float* __restrict__ b1,      // [24]
    const float* __restrict__ w2,      // [5,24]
    const float* __restrict__ b2,      // [5]
    float* __restrict__ out)           // [B,5]
{
    const int tid   = threadIdx.x;
    const int lane  = tid & 63;
    const int lo31  = lane & 31;       // weight row / tile column
    const int kh    = lane >> 5;       // K-half for MFMA fragments
    const int wid   = tid >> 6;
    const int wbase = blockIdx.x * 512 + wid * 128;   // wave's 128-elem span
    const int e0    = wbase + 2 * lane;               // this lane's even elem

    // ---------- A-fragments + bias C-init (per-wave fixed cost) ----------
    const bf16x8 A1a = pack_row8(w1 + lo31 * 24 + 8 * kh, lo31 < 24);
    const bf16x8 A1b = pack_row8(w1 + lo31 * 24 + 16, (lo31 < 24) && (kh == 0));
    const bf16x8 A2a = pack_row8(w2 + lo31 * 24 + 8 * kh, lo31 < 5);
    const bf16x8 A2b = pack_row8(w2 + lo31 * 24 + 16, (lo31 < 5) && (kh == 0));

    f32x16 c1z;
#pragma unroll
    for (int r = 0; r < 16; r++) {
        const int jb = (r & 3) + 8 * (r >> 2);        // row for kh=0
        float v = 0.0f;
        if (jb < 24) v = kh ? b1[jb + 4] : b1[jb];
        c1z[r] = v;
    }

    // ---------- issue ALL 12 dwordx4 loads up front (12KB/wave in flight) ----------
    float4 x4[Nc];                      // {even.x, even.y, odd.x, odd.y}
#pragma unroll
    for (int n = 0; n < Nc; n++)
        x4[n] = *reinterpret_cast<const float4*>(seqs + ((size_t)n * Bc + e0) * 2);
    float4 o4[7];                       // 28 floats: [0..13] even, [14..27] odd
    {
        const float4* op = reinterpret_cast<const float4*>(others + (size_t)e0 * 14);
#pragma unroll
        for (int j = 0; j < 7; j++) o4[j] = op[j];
    }

    // ---------- LSTM both elements (h0=c0=0); pack into de/dq[12] ----------
    unsigned de[12], dq[12];
#pragma unroll
    for (int n = 0; n < Nc; n++) {
        const float* w = w_ih + n * 16;   // gate rows i(0,1) f(2,3) g(4,5) o(6,7)
        const float bi0 = b_ih[n*8+0] + b_hh[n*8+0];
        const float bi1 = b_ih[n*8+1] + b_hh[n*8+1];
        const float bg0 = b_ih[n*8+4] + b_hh[n*8+4];
        const float bg1 = b_ih[n*8+5] + b_hh[n*8+5];
        const float bo0 = b_ih[n*8+6] + b_hh[n*8+6];
        const float bo1 = b_ih[n*8+7] + b_hh[n*8+7];
#pragma unroll
        for (int p = 0; p < 2; p++) {
            const float xx = p ? x4[n].z : x4[n].x;
            const float xy = p ? x4[n].w : x4[n].y;
            float gi0 = fmaf(xx, w[0],  fmaf(xy, w[1],  bi0));
            float gi1 = fmaf(xx, w[2],  fmaf(xy, w[3],  bi1));
            float gg0 = fmaf(xx, w[8],  fmaf(xy, w[9],  bg0));
            float gg1 = fmaf(xx, w[10], fmaf(xy, w[11], bg1));
            float go0 = fmaf(xx, w[12], fmaf(xy, w[13], bo0));
            float go1 = fmaf(xx, w[14], fmaf(xy, w[15], bo1));
            float c0 = sigtanh(gi0, gg0);
            float c1 = sigtanh(gi1, gg1);
            const unsigned v = cvtpk(sigtanh(go0, c0), sigtanh(go1, c1));
            if (p) dq[n] = v; else de[n] = v;
        }
    }
    // others -> features 10..23 (even: floats 0..13, odd: floats 14..27)
    de[5]  = cvtpk(o4[0].x, o4[0].y);  de[6]  = cvtpk(o4[0].z, o4[0].w);
    de[7]  = cvtpk(o4[1].x, o4[1].y);  de[8]  = cvtpk(o4[1].z, o4[1].w);
    de[9]  = cvtpk(o4[2].x, o4[2].y);  de[10] = cvtpk(o4[2].z, o4[2].w);
    de[11] = cvtpk(o4[3].x, o4[3].y);
    dq[5]  = cvtpk(o4[3].z, o4[3].w);  dq[6]  = cvtpk(o4[4].x, o4[4].y);
    dq[7]  = cvtpk(o4[4].z, o4[4].w);  dq[8]  = cvtpk(o4[5].x, o4[5].y);
    dq[9]  = cvtpk(o4[5].z, o4[5].w);  dq[10] = cvtpk(o4[6].x, o4[6].y);
    dq[11] = cvtpk(o4[6].z, o4[6].w);

    // ---------- per parity: frags -> FC1 (2 tiles) -> FC2 -> store ----------
#pragma unroll
    for (int p = 0; p < 2; p++) {
        const unsigned* d = p ? dq : de;

        unsigned b0a[4], b1a[4], b0b[4], b1b[4];
#pragma unroll
        for (int i = 0; i < 4; i++) {
            b0a[i] = d[i];     b1a[i] = d[4 + i];  swap32(b0a[i], b1a[i]);
            b0b[i] = d[8 + i]; b1b[i] = 0u;        swap32(b0b[i], b1b[i]);
        }

        f32x16 accA = c1z, accB = c1z;   // h=0 tile, h=1 tile
        accA = __builtin_amdgcn_mfma_f32_32x32x16_bf16(
            A1a, mk_frag(b0a[0], b0a[1], b0a[2], b0a[3]), accA, 0, 0, 0);
        accA = __builtin_amdgcn_mfma_f32_32x32x16_bf16(
            A1b, mk_frag(b0b[0], b0b[1], b0b[2], b0b[3]), accA, 0, 0, 0);
        accB = __builtin_amdgcn_mfma_f32_32x32x16_bf16(
            A1a, mk_frag(b1a[0], b1a[1], b1a[2], b1a[3]), accB, 0, 0, 0);
        accB = __builtin_amdgcn_mfma_f32_32x32x16_bf16(
            A1b, mk_frag(b1b[0], b1b[1], b1b[2], b1b[3]), accB, 0, 0, 0);

#pragma unroll
        for (int h = 0; h < 2; h++) {
            const f32x16 acc = h ? accB : accA;
            unsigned p0 = cvtpk(fmaxf(acc[0],  0.f), fmaxf(acc[1],  0.f));
            unsigned p1 = cvtpk(fmaxf(acc[2],  0.f), fmaxf(acc[3],  0.f));
            unsigned p2 = cvtpk(fmaxf(acc[4],  0.f), fmaxf(acc[5],  0.f));
            unsigned p3 = cvtpk(fmaxf(acc[6],  0.f), fmaxf(acc[7],  0.f));
            unsigned p4 = cvtpk(fmaxf(acc[8],  0.f), fmaxf(acc[9],  0.f));
            unsigned p5 = cvtpk(fmaxf(acc[10], 0.f), fmaxf(acc[11], 0.f));
            unsigned w0 = p0, w2 = p2;  swap32(w0, w2);
            unsigned w1v = p1, w3 = p3; swap32(w1v, w3);
            unsigned u0 = p4, u2 = 0u;  swap32(u0, u2);
            unsigned u1 = p5, u3 = 0u;  swap32(u1, u3);

            f32x16 c2;
#pragma unroll
            for (int r = 0; r < 16; r++) c2[r] = 0.0f;
            c2[0] = kh ? b2[4] : b2[0];
            if (!kh) { c2[1] = b2[1]; c2[2] = b2[2]; c2[3] = b2[3]; }
            c2 = __builtin_amdgcn_mfma_f32_32x32x16_bf16(
                A2a, mk_frag(w0, w1v, w2, w3), c2, 0, 0, 0);
            c2 = __builtin_amdgcn_mfma_f32_32x32x16_bf16(
                A2b, mk_frag(u0, u1, u2, u3), c2, 0, 0, 0);

            const float s0 = fast_sigmoid(c2[0]);
            const float s1 = fast_sigmoid(c2[1]);
            const float s2 = fast_sigmoid(c2[2]);
            const float s3 = fast_sigmoid(c2[3]);
            // tile(h,p) col c -> element wbase + 64h + 2c + p
            const int et = wbase + 64 * h + 2 * lo31 + p;
            float* o = out + (size_t)et * 5;
            if (kh == 0) {          // rows q=0..3
                o[0] = s0; o[1] = s1; o[2] = s2; o[3] = s3;
            } else {                // row q=4 (reg 0)
                o[4] = s0;
            }
        }
    }
}

extern "C" void kernel_launch(void* const* d_in, const int* in_sizes, int n_in,
                              void* d_out, int out_size, void* d_ws, size_t ws_size,
                              hipStream_t stream) {
    const float* seqs   = (const float*)d_in[0];
    const float* others = (const float*)d_in[1];
    const float* w_ih   = (const float*)d_in[2];
    // d_in[3] = w_hh : dead (h0 = 0)
    const float* b_ih   = (const float*)d_in[4];
    const float* b_hh   = (const float*)d_in[5];
    const float* w1     = (const float*)d_in[6];
    const float* b1     = (const float*)d_in[7];
    const float* w2     = (const float*)d_in[8];
    const float* b2     = (const float*)d_in[9];
    float* out = (float*)d_out;

    dim3 grid(Bc / 512), block(256);
    fused_rnn_mlp_v16<<<grid, block, 0, stream>>>(
        seqs, others, w_ih, b_ih, b_hh, w1, b1, w2, b2, out);
}

// Round 18
// 29.482 us; speedup vs baseline: 1.1116x; 1.0990x over previous
//
#include <hip/hip_runtime.h>

// B=1048576, N=5, H=2, CLS=24, OUT=5.  h0=c0=0 -> w_hh dead, f-gate dead.
// Round-18: v6 champion (29.4us: single kernel, 16x16x32 MFMA via LDS,
// single-bf16 A-frags, aliased sigma scratch, 20KB LDS) + ONE change:
// FC1/FC2 ds_reads BATCHED before the MFMAs (1 LDS round-trip latency per
// phase instead of 4 serial read->mfma->write chains). This mechanism was
// tested in r8 but confounded by __launch_bounds__(256,8): the VGPR clamp
// (32 VGPR) caused 60MB of scratch spills. Here: natural allocation.
// Batching also simplifies the scratch-aliasing proof: ALL FC2 reads
// (bytes up to 5120) complete before ANY scratch write (bytes <2048).

constexpr int Bc = 1048576;
constexpr int Nc = 5;

typedef __attribute__((ext_vector_type(8))) short bf16x8;
typedef __attribute__((ext_vector_type(4))) float f32x4;

__device__ __forceinline__ unsigned cvtpk(float lo, float hi) {
    unsigned r;
    asm("v_cvt_pk_bf16_f32 %0, %1, %2" : "=v"(r) : "v"(lo), "v"(hi));
    return r;
}
__device__ __forceinline__ float fast_sigmoid(float x) {
    return __builtin_amdgcn_rcpf(1.0f + __expf(-x));
}
// sigmoid(a)*tanh(b) with a single rcp: (e^{2b}-1) / ((e^{2b}+1)(1+e^{-a}))
__device__ __forceinline__ float sigtanh(float a, float b) {
    float ea = __expf(-a);
    float eb = __expf(2.0f * b);
    return (eb - 1.0f) * __builtin_amdgcn_rcpf((eb + 1.0f) * (1.0f + ea));
}
__device__ __forceinline__ bf16x8 as_bf16(uint4 v) {
    union { uint4 u; bf16x8 b; } c; c.u = v; return c.b;
}
// 8 consecutive K-elems of one weight row -> single-bf16 fragment (zeros if !valid)
__device__ __forceinline__ bf16x8 pack_row8(const float* row, bool valid) {
    uint4 h = make_uint4(0u, 0u, 0u, 0u);
    if (valid) {
        float4 a = *reinterpret_cast<const float4*>(row);
        float4 b = *reinterpret_cast<const float4*>(row + 4);
        h.x = cvtpk(a.x, a.y);
        h.y = cvtpk(a.z, a.w);
        h.z = cvtpk(b.x, b.y);
        h.w = cvtpk(b.z, b.w);
    }
    return as_bf16(h);
}

__global__ __launch_bounds__(256) void fused_rnn_mlp_v18(
    const float* __restrict__ seqs,    // [N,1,B,2]
    const float* __restrict__ others,  // [1,B,14]
    const float* __restrict__ w_ih,    // [N,8,2]
    const float* __restrict__ b_ih,    // [N,8]
    const float* __restrict__ b_hh,    // [N,8]
    const float* __restrict__ w1,      // [24,24]
    const float* __restrict__ b1,      // [24]
    const float* __restrict__ w2,      // [5,24]
    const float* __restrict__ b2,      // [5]
    float* __restrict__ out)           // [B,5]
{
    // per-wave region: 64 rows x 80 B = 5120 B. Sigma scratch (64 x 32 B)
    // aliases bytes [0,2048): with batched FC2 reads, all reads (bytes
    // < 5120) complete before any scratch write (bytes < 2048); traffic is
    // wave-private and the DS pipe is in-order per wave.
    __shared__ unsigned char lds_all[4 * 5120];
    const int tid  = threadIdx.x;
    const int lane = tid & 63;
    const int wid  = tid >> 6;
    const int qt   = lane >> 4;
    const int rlo  = lane & 15;
    unsigned char* wb = lds_all + wid * 5120;

    const int elem = blockIdx.x * 256 + tid;

    // ---------- hoisted global loads (12 independent, overlap latency) ----------
    float2 x[Nc];
#pragma unroll
    for (int n = 0; n < Nc; n++)
        x[n] = *reinterpret_cast<const float2*>(seqs + ((size_t)n * Bc + elem) * 2);
    float2 oth[7];
    {
        const float2* op = reinterpret_cast<const float2*>(others + (size_t)elem * 14);
#pragma unroll
        for (int j = 0; j < 7; j++) oth[j] = op[j];
    }

    // ---------- LSTM (one step, h0=c0=0), biases via uniform s_loads ----------
    float f[24];
#pragma unroll
    for (int n = 0; n < Nc; n++) {
        const float* w = w_ih + n * 16;   // gate rows i(0,1) f(2,3) g(4,5) o(6,7)
        const float bi0 = b_ih[n*8+0] + b_hh[n*8+0];
        const float bi1 = b_ih[n*8+1] + b_hh[n*8+1];
        const float bg0 = b_ih[n*8+4] + b_hh[n*8+4];
        const float bg1 = b_ih[n*8+5] + b_hh[n*8+5];
        const float bo0 = b_ih[n*8+6] + b_hh[n*8+6];
        const float bo1 = b_ih[n*8+7] + b_hh[n*8+7];
        float gi0 = fmaf(x[n].x, w[0],  fmaf(x[n].y, w[1],  bi0));
        float gi1 = fmaf(x[n].x, w[2],  fmaf(x[n].y, w[3],  bi1));
        float gg0 = fmaf(x[n].x, w[8],  fmaf(x[n].y, w[9],  bg0));
        float gg1 = fmaf(x[n].x, w[10], fmaf(x[n].y, w[11], bg1));
        float go0 = fmaf(x[n].x, w[12], fmaf(x[n].y, w[13], bo0));
        float go1 = fmaf(x[n].x, w[14], fmaf(x[n].y, w[15], bo1));
        float c0 = sigtanh(gi0, gg0);       // sigmoid(i)*tanh(g)
        float c1 = sigtanh(gi1, gg1);
        f[n*2+0] = sigtanh(go0, c0);        // sigmoid(o)*tanh(c)
        f[n*2+1] = sigtanh(go1, c1);
    }
#pragma unroll
    for (int j = 0; j < 7; j++) {
        f[10 + 2*j]     = oth[j].x;
        f[10 + 2*j + 1] = oth[j].y;
    }

    // ---------- feats -> LDS bf16 (row = lane, bytes 0..47 data, 48..63 zero) ----------
    {
        unsigned d[12];
#pragma unroll
        for (int p = 0; p < 12; p++) d[p] = cvtpk(f[2*p], f[2*p+1]);
        unsigned char* rp = wb + lane * 80;
        *reinterpret_cast<uint4*>(rp     ) = make_uint4(d[0], d[1], d[2],  d[3]);
        *reinterpret_cast<uint4*>(rp + 16) = make_uint4(d[4], d[5], d[6],  d[7]);
        *reinterpret_cast<uint4*>(rp + 32) = make_uint4(d[8], d[9], d[10], d[11]);
        *reinterpret_cast<uint4*>(rp + 48) = make_uint4(0u, 0u, 0u, 0u);
    }

    // ---------- A fragments (single bf16) + biases ----------
    const int k0 = 8 * qt;
    bf16x8 A1[2], A2;
    float4 b1v[2], b2v;
#pragma unroll
    for (int mt = 0; mt < 2; mt++) {
        const int j = rlo + 16 * mt;
        A1[mt] = pack_row8(w1 + j * 24 + k0, (j < 24) && (k0 < 24));
        if (16*mt + 4*qt < 24) {
            b1v[mt] = *reinterpret_cast<const float4*>(b1 + 16*mt + 4*qt);
        } else {
            b1v[mt] = make_float4(0.0f, 0.0f, 0.0f, 0.0f);
        }
    }
    A2 = pack_row8(w2 + rlo * 24 + k0, (rlo < 5) && (k0 < 24));
    b2v = (qt == 0) ? *reinterpret_cast<const float4*>(b2)
                    : make_float4(b2[4], 0.0f, 0.0f, 0.0f);

    // ---------- FC1: BATCHED reads -> MFMAs -> writes ----------
    // C layout [HW-verified r4]: col = lane&15 (batch row), row = 4*qt + reg.
    bf16x8 Bv[4];
#pragma unroll
    for (int nt = 0; nt < 4; nt++)
        Bv[nt] = as_bf16(*reinterpret_cast<const uint4*>(
            wb + (16*nt + rlo) * 80 + qt * 16));
#pragma unroll
    for (int nt = 0; nt < 4; nt++) {
#pragma unroll
        for (int mt = 0; mt < 2; mt++) {
            f32x4 a = { b1v[mt].x, b1v[mt].y, b1v[mt].z, b1v[mt].w };
            a = __builtin_amdgcn_mfma_f32_16x16x32_bf16(A1[mt], Bv[nt], a, 0, 0, 0);
            const unsigned p0 = cvtpk(fmaxf(a[0], 0.0f), fmaxf(a[1], 0.0f));
            const unsigned p1 = cvtpk(fmaxf(a[2], 0.0f), fmaxf(a[3], 0.0f));
            // hidden[batch][j=16mt+4qt+0..3] at bytes 2j; j>=24 writes zeros
            *reinterpret_cast<uint2*>(wb + (16*nt + rlo) * 80 + (32*mt + 8*qt)) =
                make_uint2(p0, p1);
        }
    }

    // ---------- FC2: BATCHED reads -> MFMAs -> scratch transpose ----------
#pragma unroll
    for (int nt = 0; nt < 4; nt++)
        Bv[nt] = as_bf16(*reinterpret_cast<const uint4*>(
            wb + (16*nt + rlo) * 80 + qt * 16));
#pragma unroll
    for (int nt = 0; nt < 4; nt++) {
        f32x4 a = { b2v.x, b2v.y, b2v.z, b2v.w };
        a = __builtin_amdgcn_mfma_f32_16x16x32_bf16(A2, Bv[nt], a, 0, 0, 0);
        if (qt == 0) {          // rows q=0..3
            *reinterpret_cast<float4*>(wb + (16*nt + rlo) * 32) =
                make_float4(a[0], a[1], a[2], a[3]);
        } else if (qt == 1) {   // row q=4 (reg 0)
            *reinterpret_cast<float*>(wb + (16*nt + rlo) * 32 + 16) = a[0];
        }
    }
    // each lane sigmoids + stores its OWN element's 5 outputs
    {
        const float4 v  = *reinterpret_cast<const float4*>(wb + lane * 32);
        const float  v4 = *reinterpret_cast<const float*>(wb + lane * 32 + 16);
        float* o = out + (size_t)elem * 5;
        o[0] = fast_sigmoid(v.x);
        o[1] = fast_sigmoid(v.y);
        o[2] = fast_sigmoid(v.z);
        o[3] = fast_sigmoid(v.w);
        o[4] = fast_sigmoid(v4);
    }
}

extern "C" void kernel_launch(void* const* d_in, const int* in_sizes, int n_in,
                              void* d_out, int out_size, void* d_ws, size_t ws_size,
                              hipStream_t stream) {
    const float* seqs   = (const float*)d_in[0];
    const float* others = (const float*)d_in[1];
    const float* w_ih   = (const float*)d_in[2];
    // d_in[3] = w_hh : dead (h0 = 0)
    const float* b_ih   = (const float*)d_in[4];
    const float* b_hh   = (const float*)d_in[5];
    const float* w1     = (const float*)d_in[6];
    const float* b1     = (const float*)d_in[7];
    const float* w2     = (const float*)d_in[8];
    const float* b2     = (const float*)d_in[9];
    float* out = (float*)d_out;

    dim3 grid(Bc / 256), block(256);
    fused_rnn_mlp_v18<<<grid, block, 0, stream>>>(
        seqs, others, w_ih, b_ih, b_hh, w1, b1, w2, b2, out);
}